// Round 13
// baseline (615.191 us; speedup 1.0000x reference)
//
#include <hip/hip_runtime.h>
#include <stdint.h>

// N=8192 samples, D=4096 statevector dim (fixed by reference)
#define NN 8192
#define DD 4096
#define BK 64           // K-step (one i8 MFMA covers K=64)
#define NT (DD / BK)    // 64 K-steps
#define NBLK 64         // 8192 / 128
#define LDS_T 16384     // one tile: 128 rows x 128 B (re[64]|im[64] i8, 8-slot XOR swizzle)
#define LDSBUF 32768    // A tile + B tile
#define NTILE 2080      // upper-tri incl diagonal: 64*65/2
#define GRID 2048       // 4 exact generations; blocks 0-31 run 2 tiles

typedef int   i32x4 __attribute__((ext_vector_type(4)));
typedef float f32x4 __attribute__((ext_vector_type(4)));

#define GLOAD(g, l) __builtin_amdgcn_global_load_lds( \
    (__attribute__((address_space(1))) uint32_t*)(void*)(size_t)(g), \
    (__attribute__((address_space(3))) uint32_t*)(void*)(l), 16, 0, 0)

#define VMW0() asm volatile("s_waitcnt vmcnt(0)" ::: "memory")
#define LGK0() asm volatile("s_waitcnt lgkmcnt(0)" ::: "memory")
#define SBAR() __builtin_amdgcn_s_barrier()

#define MFMA_I8(a, b, c) __builtin_amdgcn_mfma_i32_16x16x64_i8((a), (b), (c), 0, 0, 0)

// fp32 -> per-row-scaled int8 (planar re8/im8 + scales). Verified round 8.
__global__ __launch_bounds__(256) void convert_kernel(
    const float* __restrict__ re, const float* __restrict__ im,
    char* __restrict__ re8, char* __restrict__ im8, float* __restrict__ scales) {
  __shared__ float red[4];
  const int row = blockIdx.x;
  const int t = threadIdx.x;
  const float4* rr = (const float4*)(re + (size_t)row * DD);
  const float4* ir = (const float4*)(im + (size_t)row * DD);
  float4 rv[4], iv[4];
  float mx = 0.f;
#pragma unroll
  for (int c = 0; c < 4; ++c) {
    rv[c] = rr[t * 4 + c];
    iv[c] = ir[t * 4 + c];
    mx = fmaxf(mx, fmaxf(fmaxf(fabsf(rv[c].x), fabsf(rv[c].y)),
                         fmaxf(fabsf(rv[c].z), fabsf(rv[c].w))));
    mx = fmaxf(mx, fmaxf(fmaxf(fabsf(iv[c].x), fabsf(iv[c].y)),
                         fmaxf(fabsf(iv[c].z), fabsf(iv[c].w))));
  }
#pragma unroll
  for (int off = 32; off > 0; off >>= 1) mx = fmaxf(mx, __shfl_down(mx, off));
  if ((t & 63) == 0) red[t >> 6] = mx;
  __syncthreads();
  mx = fmaxf(fmaxf(red[0], red[1]), fmaxf(red[2], red[3]));
  const float inv = (mx > 1e-30f) ? (127.0f / mx) : 0.0f;
  if (t == 0) scales[row] = mx * (1.0f / 127.0f);

  i32x4 rp, ip;
#pragma unroll
  for (int c = 0; c < 4; ++c) {
    int b0 = (int)rintf(rv[c].x * inv), b1 = (int)rintf(rv[c].y * inv);
    int b2 = (int)rintf(rv[c].z * inv), b3 = (int)rintf(rv[c].w * inv);
    rp[c] = (b0 & 0xFF) | ((b1 & 0xFF) << 8) | ((b2 & 0xFF) << 16) | (b3 << 24);
    b0 = (int)rintf(iv[c].x * inv); b1 = (int)rintf(iv[c].y * inv);
    b2 = (int)rintf(iv[c].z * inv); b3 = (int)rintf(iv[c].w * inv);
    ip[c] = (b0 & 0xFF) | ((b1 & 0xFF) << 8) | ((b2 & 0xFF) << 16) | (b3 << 24);
  }
  ((i32x4*)(re8 + (size_t)row * DD))[t] = rp;
  ((i32x4*)(im8 + (size_t)row * DD))[t] = ip;
}

// r12 body (verified: 525 us, 0 bank conflicts, absmax 6.1e-5) + two changes:
//  1) anti-phase stagger: one of each co-resident CU pair sleeps ~1.3k cy at start
//     (breaks the phase-locked simultaneous LDS bursts of the 2 blocks/CU).
//  2) tail-merge: grid 2048 = 4 exact generations; blocks 0-31 process 2 tiles
//     sequentially so no 32-block straggler generation.
__global__ __launch_bounds__(256, 2) void gram_kernel(
    const char* __restrict__ re8, const char* __restrict__ im8,
    const float* __restrict__ scales,
    float* __restrict__ wts, float* __restrict__ fidp) {
  __shared__ alignas(16) char lds[2 * LDSBUF];  // 64 KB

  const int b = blockIdx.x;

  // anti-phase stagger: co-resident pair likely differs in bit 3 of blockIdx
  // (XCD round-robin: b%8 = XCD, consecutive b>>3 fill CUs). ~1350 cy delay.
  if ((b >> 3) & 1) {
    __builtin_amdgcn_s_sleep(7);
    __builtin_amdgcn_s_sleep(7);
    __builtin_amdgcn_s_sleep(7);
  }

  const int npass = (b < 32) ? 2 : 1;
  for (int pass = 0; pass < npass; ++pass) {
    // XCD-aware bijective swizzle over the first 2048 tiles; pass 1 takes the tail 32.
    const int t = (pass == 0) ? ((b & 7) * 256 + (b >> 3)) : (2048 + b);

    // t -> (bi, bj), bi <= bj (verified rounds 1-12)
    int bi = (int)(((float)(2 * NBLK + 1) -
                    sqrtf((float)((2 * NBLK + 1) * (2 * NBLK + 1) - 8 * t))) * 0.5f);
    if (bi < 0) bi = 0;
    if (bi > NBLK - 1) bi = NBLK - 1;
    while (bi > 0 && t < bi * NBLK - bi * (bi - 1) / 2) --bi;
    while (t >= (bi + 1) * NBLK - (bi + 1) * bi / 2) ++bi;
    const int bj = bi + (t - (bi * NBLK - bi * (bi - 1) / 2));

    const int brow = bi * 128, bcol = bj * 128;
    const int tid = threadIdx.x;
    const int lane = tid & 63;
    const int wid = tid >> 6;               // 4 waves
    const int wr = wid >> 1, wc = wid & 1;  // 2x2 wave grid, 64x64 out per wave
    const int t16 = tid * 16;

    // ---- staging source (pre-swizzled; LDS dest linear). Verified r8/r12 pattern ----
    const int srow = tid >> 3;                    // 0..31 (rounds add 32)
    const int slog = (tid & 7) ^ (srow & 7);
    const char* smat = (slog < 4) ? re8 : im8;
    const int scol = (slog & 3) * 16;
    const char* spA = smat + (size_t)(brow + srow) * DD + scol;
    const char* spB = smat + (size_t)(bcol + srow) * DD + scol;
    const size_t r32 = (size_t)32 * DD;

#define STAGE_A(s, bf) do { const size_t ko = (size_t)(s) * BK;   \
    char* lb_ = lds + (bf) * LDSBUF + t16;                        \
    GLOAD(spA + ko,           lb_);                               \
    GLOAD(spA + ko + r32,     lb_ + 4096);                        \
    GLOAD(spA + ko + 2 * r32, lb_ + 8192);                        \
    GLOAD(spA + ko + 3 * r32, lb_ + 12288); } while (0)
#define STAGE_B(s, bf) do { const size_t ko = (size_t)(s) * BK;   \
    char* lb_ = lds + (bf) * LDSBUF + LDS_T + t16;                \
    GLOAD(spB + ko,           lb_);                               \
    GLOAD(spB + ko + r32,     lb_ + 4096);                        \
    GLOAD(spB + ko + 2 * r32, lb_ + 8192);                        \
    GLOAD(spB + ko + 3 * r32, lb_ + 12288); } while (0)

    // ---- fragment read offsets (verified: slot_phys = kg ^ (row&7)) ----
    const int fr = lane & 15;
    const int kg = lane >> 4;
    const int reslot = (kg ^ (fr & 7)) << 4;   // re frag byte slot; im = ^64
    const int arow = (wr * 64 + fr) * 128;     // + m*2048
    const int brw  = (wc * 64 + fr) * 128;     // + n*2048

    i32x4 acc_g[4][4], acc_x[4][4], acc_y[4][4];
#pragma unroll
    for (int m = 0; m < 4; ++m)
#pragma unroll
      for (int n = 0; n < 4; ++n) {
        acc_g[m][n] = (i32x4){0, 0, 0, 0};
        acc_x[m][n] = (i32x4){0, 0, 0, 0};
        acc_y[m][n] = (i32x4){0, 0, 0, 0};
      }

    // ---- prologue ----
    STAGE_A(0, 0); STAGE_B(0, 0);
    VMW0();
    SBAR();

    for (int s = 0; s < NT; ++s) {
      const char* la = lds + (s & 1) * LDSBUF;
      const char* lb = la + LDS_T;
      const int nb = (s & 1) ^ 1;
      const bool pf = (s + 1 < NT);

      if (pf) { STAGE_A(s + 1, nb); STAGE_B(s + 1, nb); }  // 8 loads in flight all step

      i32x4 ar[4], ai[4];
#pragma unroll
      for (int m = 0; m < 4; ++m) {
        ar[m] = *(const i32x4*)(la + arow + m * 2048 + reslot);
        ai[m] = *(const i32x4*)(la + arow + m * 2048 + (reslot ^ 64));
      }
#pragma unroll
      for (int n = 0; n < 4; ++n) {
        i32x4 brf = *(const i32x4*)(lb + brw + n * 2048 + reslot);
        i32x4 bif = *(const i32x4*)(lb + brw + n * 2048 + (reslot ^ 64));
        __builtin_amdgcn_s_setprio(1);
#pragma unroll
        for (int m = 0; m < 4; ++m) {
          acc_g[m][n] = MFMA_I8(ar[m], brf, acc_g[m][n]);
          acc_g[m][n] = MFMA_I8(ai[m], bif, acc_g[m][n]);
          acc_x[m][n] = MFMA_I8(ai[m], brf, acc_x[m][n]);
          acc_y[m][n] = MFMA_I8(ar[m], bif, acc_y[m][n]);
        }
        __builtin_amdgcn_s_setprio(0);
      }

      LGK0();   // own ds_reads done before buffer re-staged next step
      VMW0();   // staging of s+1 landed (issued a full step earlier)
      SBAR();
    }

    // ---- epilogue: 16x16 C/D layout (verified): col=lane&15, row=(lane>>4)*4+reg ----
    const int grow0 = brow + wr * 64 + kg * 4;  // + m*16 + j
    const int gcol0 = bcol + wc * 64 + fr;      // + n*16

#pragma unroll
    for (int m = 0; m < 4; ++m) {
#pragma unroll
      for (int n = 0; n < 4; ++n) {
        const int gc = gcol0 + n * 16;
        const float sb = scales[gc];
        f32x4 fv;
#pragma unroll
        for (int j = 0; j < 4; ++j) {
          const int grow = grow0 + m * 16 + j;
          const float ss = scales[grow] * sb;
          const float gr = (float)acc_g[m][n][j] * ss;
          const float gi = (float)(acc_x[m][n][j] - acc_y[m][n][j]) * ss;
          fv[j] = gr * gr + gi * gi;
        }
#pragma unroll
        for (int j = 0; j < 4; ++j) {
          const int grow = grow0 + m * 16 + j;
          const float f = fv[j];
          fidp[(size_t)grow * NN + gc] = f;
          float w = 0.0f;
          if (grow < gc) w = (f >= 0.8f) ? 1.0f : ((f >= 0.5f) ? 0.5f : 0.0f);
          wts[(size_t)grow * NN + gc] = w;
        }
        if (bi != bj) {  // fid symmetric: mirror 4 contiguous rows at transposed addr
          *(f32x4*)(fidp + (size_t)gc * NN + grow0 + m * 16) = fv;
        }
      }
    }

    if (bi != bj) {
      // mirror block (bj,bi) of wts is strictly lower-triangular -> zeros
      const f32x4 zz = {0.f, 0.f, 0.f, 0.f};
      for (int i = tid; i < 4096; i += 256) {
        const int r = i >> 5, c4 = i & 31;
        *(f32x4*)(wts + (size_t)(bcol + r) * NN + brow + c4 * 4) = zz;
      }
    }

    if (pass + 1 < npass) SBAR();  // protect LDS before next pass re-stages
  }
}

extern "C" void kernel_launch(void* const* d_in, const int* in_sizes, int n_in,
                              void* d_out, int out_size, void* d_ws, size_t ws_size,
                              hipStream_t stream) {
  const float* re = (const float*)d_in[0];
  const float* im = (const float*)d_in[1];
  float* out = (float*)d_out;

  char* re8 = (char*)d_ws;                               // N*D i8
  char* im8 = re8 + (size_t)NN * DD;                     // N*D i8
  float* scales = (float*)(im8 + (size_t)NN * DD);       // N f32  (~67 MB total)

  convert_kernel<<<NN, 256, 0, stream>>>(re, im, re8, im8, scales);
  gram_kernel<<<GRID, 256, 0, stream>>>(re8, im8, scales, out, out + (size_t)NN * NN);
}